// Round 1
// baseline (202.842 us; speedup 1.0000x reference)
//
#include <hip/hip_runtime.h>

#define DEVI __device__ __forceinline__

typedef __attribute__((ext_vector_type(8))) short bf16x8;
typedef __attribute__((ext_vector_type(4))) short bf16x4;
typedef __attribute__((ext_vector_type(4))) float f32x4;

#define MFMA16 __builtin_amdgcn_mfma_f32_16x16x32_bf16

DEVI short f2bs(float f) {  // fp32 -> bf16 bits, round-nearest-even
  union { float f; unsigned u; } v; v.f = f;
  unsigned r = v.u + 0x7fffu + ((v.u >> 16) & 1u);
  return (short)(r >> 16);
}
DEVI float bs2f(short s) {
  union { unsigned u; float f; } v; v.u = ((unsigned)(unsigned short)s) << 16;
  return v.f;
}

DEVI void gload_lds16(const short* g, short* lds) {
  __builtin_amdgcn_global_load_lds(
      (const __attribute__((address_space(1))) unsigned int*)g,
      (__attribute__((address_space(3))) unsigned int*)lds, 16, 0, 0);
}

// stage a [128 rows][32 k] bf16 chunk (8 KB) packed into LDS.
// global row stride = ldg elements. 256 threads: 2 instrs each, 16 B/lane.
DEVI void stage_chunk(short* lds, const short* g, int ldg, int tid) {
#pragma unroll
  for (int it = 0; it < 2; ++it) {
    int slot = it * 256 + tid;          // 0..511
    int row  = slot >> 2;               // 4 lanes per 64 B row
    int ko   = (slot & 3) << 3;
    gload_lds16(g + (size_t)row * ldg + ko, lds + slot * 8);
  }
}

DEVI bf16x8 lds8(const short* p) { return *(const bf16x8*)p; }

DEVI void zero_acc(f32x4 (&a)[4][4]) {
  f32x4 z = {0.f, 0.f, 0.f, 0.f};
#pragma unroll
  for (int i = 0; i < 4; ++i)
#pragma unroll
    for (int j = 0; j < 4; ++j) a[i][j] = z;
}

// ---------------- K0: x [b][256][4096] fp32 -> xt [b][4096][256] bf16 ----------------
__global__ __launch_bounds__(256) void k_transpose_cast(const float* __restrict__ x,
                                                        short* __restrict__ xt) {
  __shared__ float t[64][65];
  int b = blockIdx.z;
  int c0 = blockIdx.y * 64;
  int p0 = blockIdx.x * 64;
  int tid = threadIdx.x;
  const float* xb = x + (size_t)b * 256 * 4096;
#pragma unroll
  for (int i = 0; i < 16; ++i) {
    int idx = i * 256 + tid;
    int c = idx >> 6, p = idx & 63;
    t[p][c] = xb[(size_t)(c0 + c) * 4096 + p0 + p];
  }
  __syncthreads();
  short* xtb = xt + ((size_t)b * 4096 + p0) * 256 + c0;
#pragma unroll
  for (int i = 0; i < 16; ++i) {
    int idx = i * 256 + tid;
    int p = idx >> 6, c = idx & 63;
    xtb[(size_t)p * 256 + c] = f2bs(t[p][c]);
  }
}

// ---------------- K0b: cast weights to bf16 ----------------
__global__ __launch_bounds__(256) void k_cast_w(const float* __restrict__ w1,
                                                const float* __restrict__ w2,
                                                const float* __restrict__ w3,
                                                const float* __restrict__ w4,
                                                short* __restrict__ w123,
                                                short* __restrict__ w4b) {
  int i = blockIdx.x * 256 + threadIdx.x;
  if (i < 384 * 256) {
    int r = i >> 8;
    const float* w = (r < 128) ? w1 : (r < 256 ? w2 : w3);
    w123[i] = f2bs(w[(size_t)(r & 127) * 256 + (i & 255)]);
  }
  if (i < 256 * 128) w4b[i] = f2bs(w4[i]);
}

// ---------------- K1: projections. D[pix][ch] = xt . W^T + bias ----------------
__global__ __launch_bounds__(256) void k_proj(const short* __restrict__ xt,
                                              const short* __restrict__ w123,
                                              const float* __restrict__ b1,
                                              const float* __restrict__ b2,
                                              const float* __restrict__ b3,
                                              short* __restrict__ theta,
                                              short* __restrict__ phi,
                                              short* __restrict__ gbuf) {
  __shared__ short aL[128 * 32];
  __shared__ short bL[128 * 32];
  __shared__ short oL[128 * 136];
  int tid = threadIdx.x;
  int m0 = blockIdx.x * 128;   // pixel tile
  int nb = blockIdx.y;         // 0=theta 1=phi 2=g
  int b  = blockIdx.z;
  int lane = tid & 63, wid = tid >> 6;
  int col = lane & 15, quad = lane >> 4;
  int wm = (wid >> 1) * 64, wn = (wid & 1) * 64;
  const short* A = xt + ((size_t)b * 4096 + m0) * 256;
  const short* B = w123 + (size_t)nb * 128 * 256;
  f32x4 acc[4][4];
  zero_acc(acc);
  for (int ks = 0; ks < 8; ++ks) {
    __syncthreads();
    stage_chunk(aL, A + ks * 32, 256, tid);
    stage_chunk(bL, B + ks * 32, 256, tid);
    __syncthreads();
    bf16x8 af[4], bf_[4];
#pragma unroll
    for (int mi = 0; mi < 4; ++mi) af[mi] = lds8(&aL[(wm + mi * 16 + col) * 32 + quad * 8]);
#pragma unroll
    for (int ni = 0; ni < 4; ++ni) bf_[ni] = lds8(&bL[(wn + ni * 16 + col) * 32 + quad * 8]);
#pragma unroll
    for (int mi = 0; mi < 4; ++mi)
#pragma unroll
      for (int ni = 0; ni < 4; ++ni)
        acc[mi][ni] = MFMA16(af[mi], bf_[ni], acc[mi][ni], 0, 0, 0);
  }
  const float* bias = (nb == 0) ? b1 : (nb == 1 ? b2 : b3);
  __syncthreads();
#pragma unroll
  for (int mi = 0; mi < 4; ++mi)
#pragma unroll
    for (int ni = 0; ni < 4; ++ni) {
      float bv = bias[wn + ni * 16 + col];
#pragma unroll
      for (int r = 0; r < 4; ++r)
        oL[(wm + mi * 16 + quad * 4 + r) * 136 + wn + ni * 16 + col] = f2bs(acc[mi][ni][r] + bv);
    }
  __syncthreads();
  short* O = ((nb == 0) ? theta : (nb == 1) ? phi : gbuf) + ((size_t)b * 4096 + m0) * 128;
#pragma unroll
  for (int it = 0; it < 8; ++it) {
    int slot = it * 256 + tid;            // 2048 slots of 8 shorts
    int r = slot >> 4, cp = (slot & 15) * 8;
    *(bf16x8*)(O + (size_t)r * 128 + cp) = lds8(&oL[r * 136 + cp]);
  }
}

// ---------------- K2: dpart[b][iblk][j] = sum_{i in blk} exp(S[i,j]) ----------------
__global__ __launch_bounds__(256) void k_denom(const short* __restrict__ theta,
                                               const short* __restrict__ phi,
                                               float* __restrict__ dpart) {
  __shared__ short tL[4 * 128 * 32];
  __shared__ short pL[4 * 128 * 32];
  __shared__ float part[8 * 128];
  int tid = threadIdx.x;
  int ib = blockIdx.x, jb = blockIdx.y, b = blockIdx.z;
  int lane = tid & 63, wid = tid >> 6;
  int col = lane & 15, quad = lane >> 4;
  int wi = wid >> 1;
  int wm = wi * 64, wn = (wid & 1) * 64;
  const short* T = theta + ((size_t)b * 4096 + ib * 128) * 128;
  const short* P = phi + ((size_t)b * 4096 + (size_t)jb * 128) * 128;
#pragma unroll
  for (int ks = 0; ks < 4; ++ks) {
    stage_chunk(tL + ks * 4096, T + ks * 32, 128, tid);
    stage_chunk(pL + ks * 4096, P + ks * 32, 128, tid);
  }
  __syncthreads();
  f32x4 acc[4][4];
  zero_acc(acc);
#pragma unroll
  for (int ks = 0; ks < 4; ++ks) {
    bf16x8 af[4], bf_[4];
#pragma unroll
    for (int mi = 0; mi < 4; ++mi) af[mi] = lds8(&tL[ks * 4096 + (wm + mi * 16 + col) * 32 + quad * 8]);
#pragma unroll
    for (int ni = 0; ni < 4; ++ni) bf_[ni] = lds8(&pL[ks * 4096 + (wn + ni * 16 + col) * 32 + quad * 8]);
#pragma unroll
    for (int mi = 0; mi < 4; ++mi)
#pragma unroll
      for (int ni = 0; ni < 4; ++ni)
        acc[mi][ni] = MFMA16(af[mi], bf_[ni], acc[mi][ni], 0, 0, 0);
  }
#pragma unroll
  for (int ni = 0; ni < 4; ++ni) {
    float s = 0.f;
#pragma unroll
    for (int mi = 0; mi < 4; ++mi)
#pragma unroll
      for (int r = 0; r < 4; ++r) s += __expf(acc[mi][ni][r]);
    part[(wi * 4 + quad) * 128 + wn + ni * 16 + col] = s;  // unique writer per slot
  }
  __syncthreads();
  if (tid < 128) {
    float d = 0.f;
#pragma unroll
    for (int q = 0; q < 8; ++q) d += part[q * 128 + tid];
    dpart[((size_t)(b * 32 + ib)) * 4096 + jb * 128 + tid] = d;
  }
}

// ---------------- K3: denom reduce + g'[c][j] = g[j][c]/denom[j] (bf16) ----------------
__global__ __launch_bounds__(256) void k_fold(const short* __restrict__ gbuf,
                                              const float* __restrict__ dpart,
                                              short* __restrict__ gprime) {
  __shared__ float dinv[128];
  __shared__ short t[128 * 136];
  int tid = threadIdx.x;
  int jb = blockIdx.x, b = blockIdx.y;
  int j0 = jb * 128;
  if (tid < 128) {
    float d = 0.f;
    for (int ib = 0; ib < 32; ++ib) d += dpart[((size_t)(b * 32 + ib)) * 4096 + j0 + tid];
    dinv[tid] = 1.0f / d;
  }
  __syncthreads();
  const short* G = gbuf + ((size_t)b * 4096 + j0) * 128;
#pragma unroll
  for (int it = 0; it < 8; ++it) {
    int slot = it * 256 + tid;          // 2048 x 8 shorts
    int j = slot >> 4, c8 = (slot & 15) * 8;
    bf16x8 gv = *(const bf16x8*)(G + (size_t)j * 128 + c8);
    float di = dinv[j];
#pragma unroll
    for (int e = 0; e < 8; ++e) t[(c8 + e) * 136 + j] = f2bs(bs2f(gv[e]) * di);
  }
  __syncthreads();
  short* GP = gprime + (size_t)b * 128 * 4096 + j0;
#pragma unroll
  for (int it = 0; it < 8; ++it) {
    int slot = it * 256 + tid;
    int c = slot >> 4, j8 = (slot & 15) * 8;
    *(bf16x8*)(GP + (size_t)c * 4096 + j8) = *(const bf16x8*)&t[c * 136 + j8];
  }
}

// ---------------- K4: fused S recompute + exp + PV.  Y[i][c] += exp(S[i,j]) g'[c][j] ----------------
__global__ __launch_bounds__(256, 1) void k_attn_pv(const short* __restrict__ theta,
                                                    const short* __restrict__ phi,
                                                    const short* __restrict__ gprime,
                                                    float* __restrict__ ypart) {
  __shared__ short phL[4 * 128 * 32];   // phi chunks (also theta staging pre-loop)
  __shared__ short gL[4 * 128 * 32];    // g' chunks [jks][c][32 j]
  __shared__ short pL[128 * 136];       // P tile [i][j], padded
  int tid = threadIdx.x;
  int ib = blockIdx.x, jc = blockIdx.y, b = blockIdx.z;
  int lane = tid & 63, wid = tid >> 6;
  int col = lane & 15, quad = lane >> 4;
  int wm = (wid >> 1) * 64, wn = (wid & 1) * 64;
  const short* T = theta + ((size_t)b * 4096 + ib * 128) * 128;
  const short* PH = phi + ((size_t)b * 4096 + (size_t)jc * 2048) * 128;
  const short* GP = gprime + (size_t)b * 128 * 4096 + jc * 2048;
  // theta tile -> registers (fixed across the j loop)
#pragma unroll
  for (int ks = 0; ks < 4; ++ks) stage_chunk(phL + ks * 4096, T + ks * 32, 128, tid);
  __syncthreads();
  bf16x8 ath[4][4];   // [ks][mi]
#pragma unroll
  for (int ks = 0; ks < 4; ++ks)
#pragma unroll
    for (int mi = 0; mi < 4; ++mi)
      ath[ks][mi] = lds8(&phL[ks * 4096 + (wm + mi * 16 + col) * 32 + quad * 8]);
  f32x4 accy[4][4];
  zero_acc(accy);
  for (int jt = 0; jt < 16; ++jt) {
    __syncthreads();  // previous iter's reads (or theta frag reads) complete
#pragma unroll
    for (int ks = 0; ks < 4; ++ks) {
      stage_chunk(phL + ks * 4096, PH + (size_t)jt * 16384 + ks * 32, 128, tid);
      stage_chunk(gL + ks * 4096, GP + jt * 128 + ks * 32, 4096, tid);
    }
    __syncthreads();
    // S tile
    f32x4 s[4][4];
    zero_acc(s);
#pragma unroll
    for (int ks = 0; ks < 4; ++ks) {
      bf16x8 bp[4];
#pragma unroll
      for (int ni = 0; ni < 4; ++ni) bp[ni] = lds8(&phL[ks * 4096 + (wn + ni * 16 + col) * 32 + quad * 8]);
#pragma unroll
      for (int mi = 0; mi < 4; ++mi)
#pragma unroll
        for (int ni = 0; ni < 4; ++ni)
          s[mi][ni] = MFMA16(ath[ks][mi], bp[ni], s[mi][ni], 0, 0, 0);
    }
    // exp -> P (C-layout -> A-layout via LDS)
#pragma unroll
    for (int mi = 0; mi < 4; ++mi)
#pragma unroll
      for (int ni = 0; ni < 4; ++ni)
#pragma unroll
        for (int r = 0; r < 4; ++r)
          pL[(wm + mi * 16 + quad * 4 + r) * 136 + wn + ni * 16 + col] = f2bs(__expf(s[mi][ni][r]));
    __syncthreads();
    // PV
#pragma unroll
    for (int ks = 0; ks < 4; ++ks) {
      bf16x8 ap[4], bg[4];
#pragma unroll
      for (int mi = 0; mi < 4; ++mi) ap[mi] = lds8(&pL[(wm + mi * 16 + col) * 136 + ks * 32 + quad * 8]);
#pragma unroll
      for (int ni = 0; ni < 4; ++ni) bg[ni] = lds8(&gL[ks * 4096 + (wn + ni * 16 + col) * 32 + quad * 8]);
#pragma unroll
      for (int mi = 0; mi < 4; ++mi)
#pragma unroll
        for (int ni = 0; ni < 4; ++ni)
          accy[mi][ni] = MFMA16(ap[mi], bg[ni], accy[mi][ni], 0, 0, 0);
    }
  }
  // epilogue: repack through LDS for coalesced float4 stores
  float* oF = (float*)pL;   // 64x136 floats fits in pL
  float* Y = ypart + ((size_t)(jc * 4 + b) * 4096 + ib * 128) * 128;
#pragma unroll
  for (int half = 0; half < 2; ++half) {
    __syncthreads();
    if ((wid >> 1) == half) {
#pragma unroll
      for (int mi = 0; mi < 4; ++mi)
#pragma unroll
        for (int ni = 0; ni < 4; ++ni)
#pragma unroll
          for (int r = 0; r < 4; ++r)
            oF[(mi * 16 + quad * 4 + r) * 136 + wn + ni * 16 + col] = accy[mi][ni][r];
    }
    __syncthreads();
#pragma unroll
    for (int it = 0; it < 8; ++it) {
      int slot = it * 256 + tid;        // 2048 float4 slots
      int r = slot >> 5, c4 = (slot & 31) * 4;
      *(f32x4*)(Y + (size_t)(half * 64 + r) * 128 + c4) = *(const f32x4*)&oF[r * 136 + c4];
    }
  }
}

// ---------------- K5: out[o][i] = w4 . y + b4 + x ----------------
__global__ __launch_bounds__(256) void k_out(const float* __restrict__ ypart,
                                             const float* __restrict__ w4,
                                             const float* __restrict__ b4,
                                             const float* __restrict__ x,
                                             float* __restrict__ out) {
  __shared__ short wL[4 * 128 * 32];   // [ksc][o][32c]
  __shared__ short yL[4 * 128 * 32];   // [ksc][i][32c]
  __shared__ float bLs[128];
  int tid = threadIdx.x;
  int ibk = blockIdx.x, ob = blockIdx.y, b = blockIdx.z;
  int o0 = ob * 128, i0 = ibk * 128;
  int lane = tid & 63, wid = tid >> 6;
  int col = lane & 15, quad = lane >> 4;
  int wm = (wid >> 1) * 64, wn = (wid & 1) * 64;
  const float* y0 = ypart + ((size_t)b * 4096 + i0) * 128;
  const float* y1 = ypart + ((size_t)(4 + b) * 4096 + i0) * 128;
#pragma unroll
  for (int it = 0; it < 16; ++it) {
    int slot = it * 256 + tid;          // 4096 float4 slots over [128][128]
    int r = slot >> 5, c4 = (slot & 31) * 4;
    int ks = c4 >> 5, cr = c4 & 31;
    f32x4 wv = *(const f32x4*)(w4 + (size_t)(o0 + r) * 128 + c4);
    bf16x4 wp;
#pragma unroll
    for (int e = 0; e < 4; ++e) wp[e] = f2bs(wv[e]);
    *(bf16x4*)&wL[ks * 4096 + r * 32 + cr] = wp;
    f32x4 v0 = *(const f32x4*)(y0 + (size_t)r * 128 + c4);
    f32x4 v1 = *(const f32x4*)(y1 + (size_t)r * 128 + c4);
    bf16x4 yv;
#pragma unroll
    for (int e = 0; e < 4; ++e) yv[e] = f2bs(v0[e] + v1[e]);
    *(bf16x4*)&yL[ks * 4096 + r * 32 + cr] = yv;
  }
  if (tid < 128) bLs[tid] = b4[o0 + tid];
  __syncthreads();
  f32x4 acc[4][4];
  zero_acc(acc);
#pragma unroll
  for (int ks = 0; ks < 4; ++ks) {
    bf16x8 af[4], bf_[4];
#pragma unroll
    for (int mi = 0; mi < 4; ++mi) af[mi] = lds8(&wL[ks * 4096 + (wm + mi * 16 + col) * 32 + quad * 8]);
#pragma unroll
    for (int ni = 0; ni < 4; ++ni) bf_[ni] = lds8(&yL[ks * 4096 + (wn + ni * 16 + col) * 32 + quad * 8]);
#pragma unroll
    for (int mi = 0; mi < 4; ++mi)
#pragma unroll
      for (int ni = 0; ni < 4; ++ni)
        acc[mi][ni] = MFMA16(af[mi], bf_[ni], acc[mi][ni], 0, 0, 0);
  }
  const float* X = x + ((size_t)b * 256 + o0) * 4096 + i0;
  float* O = out + ((size_t)b * 256 + o0) * 4096 + i0;
#pragma unroll
  for (int mi = 0; mi < 4; ++mi)
#pragma unroll
    for (int ni = 0; ni < 4; ++ni)
#pragma unroll
      for (int r = 0; r < 4; ++r) {
        int o = wm + mi * 16 + quad * 4 + r;
        int i = wn + ni * 16 + col;
        O[(size_t)o * 4096 + i] = acc[mi][ni][r] + X[(size_t)o * 4096 + i] + bLs[o];
      }
}

extern "C" void kernel_launch(void* const* d_in, const int* in_sizes, int n_in,
                              void* d_out, int out_size, void* d_ws, size_t ws_size,
                              hipStream_t stream) {
  const float* x  = (const float*)d_in[0];
  const float* w1 = (const float*)d_in[1];
  const float* b1 = (const float*)d_in[2];
  const float* w2 = (const float*)d_in[3];
  const float* b2 = (const float*)d_in[4];
  const float* w3 = (const float*)d_in[5];
  const float* b3 = (const float*)d_in[6];
  const float* w4 = (const float*)d_in[7];
  const float* b4 = (const float*)d_in[8];
  char* ws = (char*)d_ws;
  short* xt     = (short*)(ws + 0);          // 4*4096*256*2  = 8388608
  short* w123   = (short*)(ws + 8388608);    // 384*256*2     = 196608
  short* w4b    = (short*)(ws + 8585216);    // 256*128*2     = 65536
  short* theta  = (short*)(ws + 8650752);    // 4*4096*128*2  = 4194304
  short* phi    = (short*)(ws + 12845056);   // 4194304
  short* gbuf   = (short*)(ws + 17039360);   // 4194304
  short* gprime = (short*)(ws + 21233664);   // 4194304
  float* dpart  = (float*)(ws + 25427968);   // 4*32*4096*4   = 2097152
  float* ypart  = (float*)(ws + 27525120);   // 2*4*4096*128*4= 16777216
  float* out    = (float*)d_out;
  (void)w4b; (void)in_sizes; (void)n_in; (void)out_size; (void)ws_size;

  k_transpose_cast<<<dim3(64, 4, 4), dim3(256), 0, stream>>>(x, xt);
  k_cast_w<<<dim3(384), dim3(256), 0, stream>>>(w1, w2, w3, w4, w123, w4b);
  k_proj<<<dim3(32, 3, 4), dim3(256), 0, stream>>>(xt, w123, b1, b2, b3, theta, phi, gbuf);
  k_denom<<<dim3(32, 32, 4), dim3(256), 0, stream>>>(theta, phi, dpart);
  k_fold<<<dim3(32, 4), dim3(256), 0, stream>>>(gbuf, dpart, gprime);
  k_attn_pv<<<dim3(32, 2, 4), dim3(256), 0, stream>>>(theta, phi, gprime, ypart);
  k_out<<<dim3(32, 2, 4), dim3(256), 0, stream>>>(ypart, w4, b4, x, out);
}

// Round 2
// 174.919 us; speedup vs baseline: 1.1596x; 1.1596x over previous
//
#include <hip/hip_runtime.h>

#define DEVI __device__ __forceinline__

typedef __attribute__((ext_vector_type(8))) short bf16x8;
typedef __attribute__((ext_vector_type(4))) short bf16x4;
typedef __attribute__((ext_vector_type(4))) float f32x4;

#define MFMA16 __builtin_amdgcn_mfma_f32_16x16x32_bf16

DEVI short f2bs(float f) {  // fp32 -> bf16 bits, round-nearest-even
  union { float f; unsigned u; } v; v.f = f;
  unsigned r = v.u + 0x7fffu + ((v.u >> 16) & 1u);
  return (short)(r >> 16);
}
DEVI float bs2f(short s) {
  union { unsigned u; float f; } v; v.u = ((unsigned)(unsigned short)s) << 16;
  return v.f;
}

DEVI void gload_lds16(const short* g, short* lds) {
  __builtin_amdgcn_global_load_lds(
      (const __attribute__((address_space(1))) unsigned int*)g,
      (__attribute__((address_space(3))) unsigned int*)lds, 16, 0, 0);
}

// stage a [128 rows][32 k] bf16 chunk (8 KB) packed into LDS. 2 instrs/thread.
DEVI void stage_chunk(short* lds, const short* g, int ldg, int tid) {
#pragma unroll
  for (int it = 0; it < 2; ++it) {
    int slot = it * 256 + tid;          // 0..511
    int row  = slot >> 2;               // 4 lanes per 64 B row
    int ko   = (slot & 3) << 3;
    gload_lds16(g + (size_t)row * ldg + ko, lds + slot * 8);
  }
}

// stage a [64 rows][32 k] bf16 chunk (4 KB). 1 instr/thread.
DEVI void stage_chunk64(short* lds, const short* g, int ldg, int tid) {
  int row = tid >> 2, ko = (tid & 3) << 3;
  gload_lds16(g + (size_t)row * ldg + ko, lds + tid * 8);
}

DEVI bf16x8 lds8(const short* p) { return *(const bf16x8*)p; }

DEVI void zero_acc(f32x4 (&a)[4][4]) {
  f32x4 z = {0.f, 0.f, 0.f, 0.f};
#pragma unroll
  for (int i = 0; i < 4; ++i)
#pragma unroll
    for (int j = 0; j < 4; ++j) a[i][j] = z;
}

// ---------------- K0: x [b][256][4096] fp32 -> xt [b][4096][256] bf16 ----------------
__global__ __launch_bounds__(256) void k_transpose_cast(const float* __restrict__ x,
                                                        short* __restrict__ xt) {
  __shared__ float t[64][65];
  int b = blockIdx.z;
  int c0 = blockIdx.y * 64;
  int p0 = blockIdx.x * 64;
  int tid = threadIdx.x;
  const float* xb = x + (size_t)b * 256 * 4096;
#pragma unroll
  for (int i = 0; i < 16; ++i) {
    int idx = i * 256 + tid;
    int c = idx >> 6, p = idx & 63;
    t[p][c] = xb[(size_t)(c0 + c) * 4096 + p0 + p];
  }
  __syncthreads();
  short* xtb = xt + ((size_t)b * 4096 + p0) * 256 + c0;
#pragma unroll
  for (int i = 0; i < 16; ++i) {
    int idx = i * 256 + tid;
    int p = idx >> 6, c = idx & 63;
    xtb[(size_t)p * 256 + c] = f2bs(t[p][c]);
  }
}

// ---------------- K0b: cast w1/w2/w3 to bf16 (concatenated [384][256]) ----------------
__global__ __launch_bounds__(256) void k_cast_w(const float* __restrict__ w1,
                                                const float* __restrict__ w2,
                                                const float* __restrict__ w3,
                                                short* __restrict__ w123) {
  int i = blockIdx.x * 256 + threadIdx.x;
  if (i < 384 * 256) {
    int r = i >> 8;
    const float* w = (r < 128) ? w1 : (r < 256 ? w2 : w3);
    w123[i] = f2bs(w[(size_t)(r & 127) * 256 + (i & 255)]);
  }
}

// ---------------- K1: projections. D[pix][ch] = xt . W^T + bias ----------------
__global__ __launch_bounds__(256) void k_proj(const short* __restrict__ xt,
                                              const short* __restrict__ w123,
                                              const float* __restrict__ b1,
                                              const float* __restrict__ b2,
                                              const float* __restrict__ b3,
                                              short* __restrict__ theta,
                                              short* __restrict__ phi,
                                              short* __restrict__ gbuf) {
  __shared__ short aL[128 * 32];
  __shared__ short bL[128 * 32];
  __shared__ short oL[128 * 136];
  int tid = threadIdx.x;
  int m0 = blockIdx.x * 128;   // pixel tile
  int nb = blockIdx.y;         // 0=theta 1=phi 2=g
  int b  = blockIdx.z;
  int lane = tid & 63, wid = tid >> 6;
  int col = lane & 15, quad = lane >> 4;
  int wm = (wid >> 1) * 64, wn = (wid & 1) * 64;
  const short* A = xt + ((size_t)b * 4096 + m0) * 256;
  const short* B = w123 + (size_t)nb * 128 * 256;
  f32x4 acc[4][4];
  zero_acc(acc);
  for (int ks = 0; ks < 8; ++ks) {
    __syncthreads();
    stage_chunk(aL, A + ks * 32, 256, tid);
    stage_chunk(bL, B + ks * 32, 256, tid);
    __syncthreads();
    bf16x8 af[4], bf_[4];
#pragma unroll
    for (int mi = 0; mi < 4; ++mi) af[mi] = lds8(&aL[(wm + mi * 16 + col) * 32 + quad * 8]);
#pragma unroll
    for (int ni = 0; ni < 4; ++ni) bf_[ni] = lds8(&bL[(wn + ni * 16 + col) * 32 + quad * 8]);
#pragma unroll
    for (int mi = 0; mi < 4; ++mi)
#pragma unroll
      for (int ni = 0; ni < 4; ++ni)
        acc[mi][ni] = MFMA16(af[mi], bf_[ni], acc[mi][ni], 0, 0, 0);
  }
  const float* bias = (nb == 0) ? b1 : (nb == 1 ? b2 : b3);
  __syncthreads();
#pragma unroll
  for (int mi = 0; mi < 4; ++mi)
#pragma unroll
    for (int ni = 0; ni < 4; ++ni) {
      float bv = bias[wn + ni * 16 + col];
#pragma unroll
      for (int r = 0; r < 4; ++r)
        oL[(wm + mi * 16 + quad * 4 + r) * 136 + wn + ni * 16 + col] = f2bs(acc[mi][ni][r] + bv);
    }
  __syncthreads();
  short* O = ((nb == 0) ? theta : (nb == 1) ? phi : gbuf) + ((size_t)b * 4096 + m0) * 128;
#pragma unroll
  for (int it = 0; it < 8; ++it) {
    int slot = it * 256 + tid;            // 2048 slots of 8 shorts
    int r = slot >> 4, cp = (slot & 15) * 8;
    *(bf16x8*)(O + (size_t)r * 128 + cp) = lds8(&oL[r * 136 + cp]);
  }
}

// ---------------- K2: denom. block (ib, jc, b): theta in regs, stream 8 phi tiles ----------------
__global__ __launch_bounds__(256, 2) void k_denom(const short* __restrict__ theta,
                                                  const short* __restrict__ phi,
                                                  float* __restrict__ dpart) {
  __shared__ short phB[2][16384];   // [buf][4 ks][128 j][32 k]
  __shared__ float part[1024];      // [8][128]
  int tid = threadIdx.x;
  int ib = blockIdx.x, jc = blockIdx.y, b = blockIdx.z;
  int lane = tid & 63, wid = tid >> 6;
  int col = lane & 15, quad = lane >> 4;
  int wm = (wid >> 1) * 64, wn = (wid & 1) * 64;
  const short* T = theta + ((size_t)b * 4096 + ib * 128) * 128;
  const short* P = phi + ((size_t)b * 4096 + (size_t)jc * 1024) * 128;
  // theta [128][128] staged across both buffers, then to registers
  short* Lb = &phB[0][0];
#pragma unroll
  for (int ks = 0; ks < 4; ++ks) stage_chunk(Lb + ks * 8192, T + ks * 32, 128, tid);
  __syncthreads();
  bf16x8 ath[4][4];
#pragma unroll
  for (int ks = 0; ks < 4; ++ks)
#pragma unroll
    for (int mi = 0; mi < 4; ++mi)
      ath[ks][mi] = lds8(&Lb[ks * 8192 + (wm + mi * 16 + col) * 32 + quad * 8]);
  __syncthreads();
  // prologue stage jt=0
#pragma unroll
  for (int ks = 0; ks < 4; ++ks) stage_chunk(&phB[0][0] + ks * 4096, P + ks * 32, 128, tid);
  for (int jt = 0; jt < 8; ++jt) {
    int cur = jt & 1;
    __syncthreads();   // stage(jt) complete; part readers of jt-1 done
    if (jt < 7) {
      const short* Pn = P + (size_t)(jt + 1) * 128 * 128;
#pragma unroll
      for (int ks = 0; ks < 4; ++ks) stage_chunk(&phB[cur ^ 1][0] + ks * 4096, Pn + ks * 32, 128, tid);
    }
    f32x4 sacc[4][4];
    zero_acc(sacc);
#pragma unroll
    for (int ks = 0; ks < 4; ++ks) {
      bf16x8 bp[4];
#pragma unroll
      for (int ni = 0; ni < 4; ++ni) bp[ni] = lds8(&phB[cur][ks * 4096 + (wn + ni * 16 + col) * 32 + quad * 8]);
#pragma unroll
      for (int mi = 0; mi < 4; ++mi)
#pragma unroll
        for (int ni = 0; ni < 4; ++ni)
          sacc[mi][ni] = MFMA16(ath[ks][mi], bp[ni], sacc[mi][ni], 0, 0, 0);
    }
#pragma unroll
    for (int ni = 0; ni < 4; ++ni) {
      float s = 0.f;
#pragma unroll
      for (int mi = 0; mi < 4; ++mi)
#pragma unroll
        for (int r = 0; r < 4; ++r) s += __expf(sacc[mi][ni][r]);
      part[((wid >> 1) * 4 + quad) * 128 + wn + ni * 16 + col] = s;
    }
    __syncthreads();
    if (tid < 128) {
      float d = 0.f;
#pragma unroll
      for (int q = 0; q < 8; ++q) d += part[q * 128 + tid];
      dpart[((size_t)(b * 32 + ib)) * 4096 + jc * 1024 + jt * 128 + tid] = d;
    }
  }
}

// ---------------- K3: denom reduce + g'[c][j] = g[j][c]/denom[j] (bf16) ----------------
__global__ __launch_bounds__(256) void k_fold(const short* __restrict__ gbuf,
                                              const float* __restrict__ dpart,
                                              short* __restrict__ gprime) {
  __shared__ float dinv[128];
  __shared__ short t[128 * 136];
  int tid = threadIdx.x;
  int jb = blockIdx.x, b = blockIdx.y;
  int j0 = jb * 128;
  if (tid < 128) {
    float d = 0.f;
    for (int ib = 0; ib < 32; ++ib) d += dpart[((size_t)(b * 32 + ib)) * 4096 + j0 + tid];
    dinv[tid] = 1.0f / d;
  }
  __syncthreads();
  const short* G = gbuf + ((size_t)b * 4096 + j0) * 128;
#pragma unroll
  for (int it = 0; it < 8; ++it) {
    int slot = it * 256 + tid;          // 2048 x 8 shorts
    int j = slot >> 4, c8 = (slot & 15) * 8;
    bf16x8 gv = *(const bf16x8*)(G + (size_t)j * 128 + c8);
    float di = dinv[j];
#pragma unroll
    for (int e = 0; e < 8; ++e) t[(c8 + e) * 136 + j] = f2bs(bs2f(gv[e]) * di);
  }
  __syncthreads();
  short* GP = gprime + (size_t)b * 128 * 4096 + j0;
#pragma unroll
  for (int it = 0; it < 8; ++it) {
    int slot = it * 256 + tid;
    int c = slot >> 4, j8 = (slot & 15) * 8;
    *(bf16x8*)(GP + (size_t)c * 4096 + j8) = *(const bf16x8*)&t[c * 136 + j8];
  }
}

// ---------------- K4: fused S recompute + exp + PV, dbuf, 2 blocks/CU ----------------
// LDS map (shorts): ph[0]=L+0 (8192), ph[1]=L+8192, gp[0]=L+16384, gp[1]=L+24576, P=L+32768 (8192)
__global__ __launch_bounds__(256, 2) void k_attn_pv(const short* __restrict__ theta,
                                                    const short* __restrict__ phi,
                                                    const short* __restrict__ gprime,
                                                    short* __restrict__ ypart) {
  __shared__ short L[40960];   // 80 KB exactly -> 2 blocks/CU
  int tid = threadIdx.x;
  int ib = blockIdx.x, jc = blockIdx.y, b = blockIdx.z;
  int lane = tid & 63, wid = tid >> 6;
  int col = lane & 15, quad = lane >> 4;
  int wm = (wid >> 1) * 64;
  int wnS = (wid & 1) * 32;    // S phase: n = j (64)
  int wnV = (wid & 1) * 64;    // PV phase: n = c (128)
  const short* T = theta + ((size_t)b * 4096 + ib * 128) * 128;
  const short* PH = phi + ((size_t)b * 4096 + (size_t)jc * 1024) * 128;
  const short* GP = gprime + (size_t)b * 128 * 4096 + jc * 1024;
  short* pP = L + 32768;
  // theta [128 i][128 k] staged into L[0..32767], then to registers
#pragma unroll
  for (int ks = 0; ks < 4; ++ks) stage_chunk(L + ks * 8192, T + ks * 32, 128, tid);
  __syncthreads();
  bf16x8 ath[4][4];
#pragma unroll
  for (int ks = 0; ks < 4; ++ks)
#pragma unroll
    for (int mi = 0; mi < 4; ++mi)
      ath[ks][mi] = lds8(&L[ks * 8192 + (wm + mi * 16 + col) * 32 + quad * 8]);
  __syncthreads();
  // prologue: stage jt=0 (phi into ph[0], g' into gp[0])
#pragma unroll
  for (int ks = 0; ks < 4; ++ks) stage_chunk64(L + ks * 2048, PH + ks * 32, 128, tid);
#pragma unroll
  for (int jh = 0; jh < 2; ++jh) stage_chunk(L + 16384 + jh * 4096, GP + jh * 32, 4096, tid);
  f32x4 accy[4][4];
  zero_acc(accy);
  for (int jt = 0; jt < 16; ++jt) {
    int cur = jt & 1;
    short* phc = L + cur * 8192;
    short* phn = L + (cur ^ 1) * 8192;
    short* gpc = L + 16384 + cur * 8192;
    short* gpn = L + 16384 + (cur ^ 1) * 8192;
    __syncthreads();   // stage(jt) complete; prior-iter LDS reads done
    if (jt < 15) {     // prefetch phi(jt+1) — overlaps S phase
      const short* PHn = PH + (size_t)(jt + 1) * 64 * 128;
#pragma unroll
      for (int ks = 0; ks < 4; ++ks) stage_chunk64(phn + ks * 2048, PHn + ks * 32, 128, tid);
    }
    // S = theta . phi^T  (m=i 128, n=j 64, K=128)
    f32x4 s[4][2];
#pragma unroll
    for (int mi = 0; mi < 4; ++mi)
#pragma unroll
      for (int ni = 0; ni < 2; ++ni) s[mi][ni] = (f32x4){0.f, 0.f, 0.f, 0.f};
#pragma unroll
    for (int ks = 0; ks < 4; ++ks) {
      bf16x8 bp[2];
#pragma unroll
      for (int ni = 0; ni < 2; ++ni) bp[ni] = lds8(&phc[ks * 2048 + (wnS + ni * 16 + col) * 32 + quad * 8]);
#pragma unroll
      for (int mi = 0; mi < 4; ++mi)
#pragma unroll
        for (int ni = 0; ni < 2; ++ni)
          s[mi][ni] = MFMA16(ath[ks][mi], bp[ni], s[mi][ni], 0, 0, 0);
    }
    // exp -> P tile, packed [2 cj][128 i][32 j] with XOR-swizzled 8-groups (2-way = free)
#pragma unroll
    for (int mi = 0; mi < 4; ++mi)
#pragma unroll
      for (int ni = 0; ni < 2; ++ni) {
        int jj = wnS + ni * 16 + col;       // 0..63
        int cj = jj >> 5, jg = (jj >> 3) & 3, jl = jj & 7;
#pragma unroll
        for (int r = 0; r < 4; ++r) {
          int i = wm + mi * 16 + quad * 4 + r;
          pP[cj * 4096 + i * 32 + (((jg ^ (i >> 2)) & 3) << 3) + jl] = f2bs(__expf(s[mi][ni][r]));
        }
      }
    __syncthreads();   // P visible (drains phi prefetch too)
    if (jt < 15) {     // prefetch g'(jt+1) — overlaps PV phase
      const short* GPn = GP + (jt + 1) * 64;
#pragma unroll
      for (int jh = 0; jh < 2; ++jh) stage_chunk(gpn + jh * 4096, GPn + jh * 32, 4096, tid);
    }
    // Y += P . g'^T  (m=i 128, n=c 128, K=64)
#pragma unroll
    for (int ks = 0; ks < 2; ++ks) {
      bf16x8 ap[4], bg[4];
#pragma unroll
      for (int mi = 0; mi < 4; ++mi) {
        int i = wm + mi * 16 + col;
        ap[mi] = lds8(&pP[ks * 4096 + i * 32 + (((quad ^ (i >> 2)) & 3) << 3)]);
      }
#pragma unroll
      for (int ni = 0; ni < 4; ++ni) bg[ni] = lds8(&gpc[ks * 4096 + (wnV + ni * 16 + col) * 32 + quad * 8]);
#pragma unroll
      for (int mi = 0; mi < 4; ++mi)
#pragma unroll
        for (int ni = 0; ni < 4; ++ni)
          accy[mi][ni] = MFMA16(ap[mi], bg[ni], accy[mi][ni], 0, 0, 0);
    }
  }
  // epilogue: bf16 partial, repacked via pP (two 64-row halves), coalesced 16 B stores
  short* Yp = ypart + ((size_t)(jc * 4 + b) * 4096 + (size_t)ib * 128) * 128;
#pragma unroll
  for (int half = 0; half < 2; ++half) {
    __syncthreads();
    if ((wid >> 1) == half) {
#pragma unroll
      for (int mi = 0; mi < 4; ++mi)
#pragma unroll
        for (int ni = 0; ni < 4; ++ni)
#pragma unroll
          for (int r = 0; r < 4; ++r)
            pP[(mi * 16 + quad * 4 + r) * 128 + wnV + ni * 16 + col] = f2bs(accy[mi][ni][r]);
    }
    __syncthreads();
#pragma unroll
    for (int it = 0; it < 4; ++it) {
      int slot = it * 256 + tid;        // 1024 slots of 8 shorts over [64][128]
      int r = slot >> 4, c8 = (slot & 15) * 8;
      *(bf16x8*)(Yp + (size_t)(half * 64 + r) * 128 + c8) = lds8(&pP[r * 128 + c8]);
    }
  }
}

// ---------------- K5: out[o][i] = w4 . (sum of 4 bf16 ypart partials) + b4 + x ----------------
__global__ __launch_bounds__(256) void k_out(const short* __restrict__ ypart,
                                             const float* __restrict__ w4,
                                             const float* __restrict__ b4,
                                             const float* __restrict__ x,
                                             float* __restrict__ out) {
  __shared__ short wL[4 * 4096];   // [ksc][o][32c]
  __shared__ short yL[4 * 4096];   // [ksc][i][32c]
  __shared__ float bLs[128];
  int tid = threadIdx.x;
  int ibk = blockIdx.x, ob = blockIdx.y, b = blockIdx.z;
  int o0 = ob * 128, i0 = ibk * 128;
  int lane = tid & 63, wid = tid >> 6;
  int col = lane & 15, quad = lane >> 4;
  int wm = (wid >> 1) * 64, wn = (wid & 1) * 64;
#pragma unroll
  for (int it = 0; it < 16; ++it) {
    int slot = it * 256 + tid;          // 4096 float4 slots over w4 [128][128]
    int r = slot >> 5, c4 = (slot & 31) * 4;
    int ks = c4 >> 5, cr = c4 & 31;
    f32x4 wv = *(const f32x4*)(w4 + (size_t)(o0 + r) * 128 + c4);
    bf16x4 wp;
#pragma unroll
    for (int e = 0; e < 4; ++e) wp[e] = f2bs(wv[e]);
    *(bf16x4*)&wL[ks * 4096 + r * 32 + cr] = wp;
  }
#pragma unroll
  for (int it = 0; it < 8; ++it) {
    int slot = it * 256 + tid;          // 2048 slots of 8 over y [128][128]
    int r = slot >> 4, c8 = (slot & 15) * 8;
    int ks = c8 >> 5, cr = c8 & 31;
    float a8[8];
#pragma unroll
    for (int e = 0; e < 8; ++e) a8[e] = 0.f;
#pragma unroll
    for (int p = 0; p < 4; ++p) {
      bf16x8 v = *(const bf16x8*)(ypart + ((size_t)(p * 4 + b) * 4096 + i0 + r) * 128 + c8);
#pragma unroll
      for (int e = 0; e < 8; ++e) a8[e] += bs2f(v[e]);
    }
    bf16x8 yv;
#pragma unroll
    for (int e = 0; e < 8; ++e) yv[e] = f2bs(a8[e]);
    *(bf16x8*)&yL[ks * 4096 + r * 32 + cr] = yv;
  }
  if (tid < 128) bLs[tid] = b4[o0 + tid];
  __syncthreads();
  f32x4 acc[4][4];
  zero_acc(acc);
#pragma unroll
  for (int ks = 0; ks < 4; ++ks) {
    bf16x8 af[4], bf_[4];
#pragma unroll
    for (int mi = 0; mi < 4; ++mi) af[mi] = lds8(&wL[ks * 4096 + (wm + mi * 16 + col) * 32 + quad * 8]);
#pragma unroll
    for (int ni = 0; ni < 4; ++ni) bf_[ni] = lds8(&yL[ks * 4096 + (wn + ni * 16 + col) * 32 + quad * 8]);
#pragma unroll
    for (int mi = 0; mi < 4; ++mi)
#pragma unroll
      for (int ni = 0; ni < 4; ++ni)
        acc[mi][ni] = MFMA16(af[mi], bf_[ni], acc[mi][ni], 0, 0, 0);
  }
  const float* X = x + ((size_t)b * 256 + o0) * 4096 + i0;
  float* O = out + ((size_t)b * 256 + o0) * 4096 + i0;
#pragma unroll
  for (int mi = 0; mi < 4; ++mi)
#pragma unroll
    for (int ni = 0; ni < 4; ++ni)
#pragma unroll
      for (int r = 0; r < 4; ++r) {
        int o = wm + mi * 16 + quad * 4 + r;
        int i = wn + ni * 16 + col;
        O[(size_t)o * 4096 + i] = acc[mi][ni][r] + X[(size_t)o * 4096 + i] + bLs[o];
      }
}

extern "C" void kernel_launch(void* const* d_in, const int* in_sizes, int n_in,
                              void* d_out, int out_size, void* d_ws, size_t ws_size,
                              hipStream_t stream) {
  const float* x  = (const float*)d_in[0];
  const float* w1 = (const float*)d_in[1];
  const float* b1 = (const float*)d_in[2];
  const float* w2 = (const float*)d_in[3];
  const float* b2 = (const float*)d_in[4];
  const float* w3 = (const float*)d_in[5];
  const float* b3 = (const float*)d_in[6];
  const float* w4 = (const float*)d_in[7];
  const float* b4 = (const float*)d_in[8];
  char* ws = (char*)d_ws;
  short* xt     = (short*)(ws + 0);          // 4*4096*256*2   = 8,388,608
  short* w123   = (short*)(ws + 8388608);    // 384*256*2      =   196,608
  short* theta  = (short*)(ws + 8585216);    // 4*4096*128*2   = 4,194,304
  short* phi    = (short*)(ws + 12779520);   // 4,194,304
  short* gbuf   = (short*)(ws + 16973824);   // 4,194,304
  short* gprime = (short*)(ws + 21168128);   // 4,194,304
  float* dpart  = (float*)(ws + 25362432);   // 4*32*4096*4    = 2,097,152
  short* ypart  = (short*)(ws + 27459584);   // 4*4*4096*128*2 = 16,777,216 (end 44,236,800)
  float* out    = (float*)d_out;
  (void)in_sizes; (void)n_in; (void)out_size; (void)ws_size;

  k_transpose_cast<<<dim3(64, 4, 4), dim3(256), 0, stream>>>(x, xt);
  k_cast_w<<<dim3(384), dim3(256), 0, stream>>>(w1, w2, w3, w123);
  k_proj<<<dim3(32, 3, 4), dim3(256), 0, stream>>>(xt, w123, b1, b2, b3, theta, phi, gbuf);
  k_denom<<<dim3(32, 4, 4), dim3(256), 0, stream>>>(theta, phi, dpart);
  k_fold<<<dim3(32, 4), dim3(256), 0, stream>>>(gbuf, dpart, gprime);
  k_attn_pv<<<dim3(32, 4, 4), dim3(256), 0, stream>>>(theta, phi, gprime, ypart);
  k_out<<<dim3(32, 2, 4), dim3(256), 0, stream>>>(ypart, w4, b4, x, out);
}